// Round 3
// baseline (435.673 us; speedup 1.0000x reference)
//
#include <hip/hip_runtime.h>

#define D 4096
#define RANK 1024
#define UELEMS 4194304ULL   // D*RANK
#define NTOT 16777216ULL    // 4^12 = D*D
#define QSCALE 16000.0f

typedef __attribute__((ext_vector_type(4))) int i32x4;

__device__ float g_inv_tr[1];
__device__ float g_scale[D];
__device__ float g_mdre[16];   // M-dagger tables: M†[s][i][j] = conj(M[s][j][i])
__device__ float g_mdim[16];

static __device__ __forceinline__ void load_lds16(const void* g, void* l) {
    __builtin_amdgcn_global_load_lds(
        (const __attribute__((address_space(1))) unsigned int*)g,
        (__attribute__((address_space(3))) unsigned int*)l, 16, 0, 0);
}

#define MFMA_I8 __builtin_amdgcn_mfma_i32_16x16x64_i8

// ---------------------------------------------------------------------------
// i8 split quantization of W = [Ur | Ui] with per-row scale (verified r6).
// ---------------------------------------------------------------------------
__global__ __launch_bounds__(256) void convert_w_i8(const float* __restrict__ P,
                                                    const float* __restrict__ Mre,
                                                    const float* __restrict__ Mim,
                                                    char* __restrict__ Wh,
                                                    char* __restrict__ Wl)
{
    if (blockIdx.x == 0 && threadIdx.x < 16) {
        const int s = threadIdx.x >> 2, i = (threadIdx.x >> 1) & 1, j = threadIdx.x & 1;
        g_mdre[threadIdx.x] =  Mre[s * 4 + j * 2 + i];
        g_mdim[threadIdx.x] = -Mim[s * 4 + j * 2 + i];
    }

    const int w = threadIdx.x >> 6, lane = threadIdx.x & 63;
    const int row = blockIdx.x * 4 + w;

    float ur[16], ui[16];
    const float* pr = P + (size_t)row * RANK + lane * 16;
    const float* pi = P + UELEMS + (size_t)row * RANK + lane * 16;
    #pragma unroll
    for (int q = 0; q < 4; ++q) {
        const float4 a = ((const float4*)pr)[q];
        const float4 b = ((const float4*)pi)[q];
        ur[q * 4 + 0] = a.x; ur[q * 4 + 1] = a.y; ur[q * 4 + 2] = a.z; ur[q * 4 + 3] = a.w;
        ui[q * 4 + 0] = b.x; ui[q * 4 + 1] = b.y; ui[q * 4 + 2] = b.z; ui[q * 4 + 3] = b.w;
    }
    float mx = 0.f;
    #pragma unroll
    for (int e = 0; e < 16; ++e)
        mx = fmaxf(mx, fmaxf(fabsf(ur[e]), fabsf(ui[e])));
    #pragma unroll
    for (int off = 1; off < 64; off <<= 1)
        mx = fmaxf(mx, __shfl_xor(mx, off));
    const float inv = mx > 0.f ? QSCALE / mx : 0.f;
    if (lane == 0) g_scale[row] = mx / QSCALE;

    int hr[16], lr[16], hi[16], li[16];
    #pragma unroll
    for (int e = 0; e < 16; ++e) {
        float q = ur[e] * inv;
        float hf = rintf(q * 0.0078125f);
        hr[e] = (int)hf; lr[e] = (int)rintf(q - 128.f * hf);
        q = ui[e] * inv;
        hf = rintf(q * 0.0078125f);
        hi[e] = (int)hf; li[e] = (int)rintf(q - 128.f * hf);
    }
    uint4 phr, plr, phi, pli;
    unsigned* dst[4] = {(unsigned*)&phr, (unsigned*)&plr, (unsigned*)&phi, (unsigned*)&pli};
    #pragma unroll
    for (int q = 0; q < 4; ++q) {
        unsigned a = 0, b = 0, c = 0, d = 0;
        #pragma unroll
        for (int k = 0; k < 4; ++k) {
            const int sh = k * 8;
            a |= (unsigned)(hr[q * 4 + k] & 255) << sh;
            b |= (unsigned)(lr[q * 4 + k] & 255) << sh;
            c |= (unsigned)(hi[q * 4 + k] & 255) << sh;
            d |= (unsigned)(li[q * 4 + k] & 255) << sh;
        }
        dst[0][q] = a; dst[1][q] = b; dst[2][q] = c; dst[3][q] = d;
    }
    const size_t b1 = (size_t)row * 2048 + lane * 16;
    *(uint4*)&Wh[b1] = phr;          *(uint4*)&Wl[b1] = plr;
    *(uint4*)&Wh[b1 + 1024] = phi;   *(uint4*)&Wl[b1 + 1024] = pli;
}

// ---------------------------------------------------------------------------
// Fused Hermitian GEMM in i8. r13: barrier-free K-loop interior.
// The mid-kt s_barriers were pure scheduling devices (35% MfmaUtil showed
// they serialized the LDS and MFMA bursts); the only correctness sync is the
// end-of-kt __syncthreads (publishes staging, protects buffer swap).
// All 6 staging loads issue at the TOP of kt (target buffer's readers
// finished at the previous __syncthreads), so the end-of-kt vmcnt drain sits
// behind a full kt of compute. Compiler emits counted lgkm waits per MFMA
// group (verified behavior, m97 r109).
// ---------------------------------------------------------------------------
__global__ __launch_bounds__(512, 2) void gemm_rho_i8(const char* __restrict__ Wh,
                                                      const char* __restrict__ Wl,
                                                      float2* __restrict__ rho)
{
    __shared__ __align__(16) char sA[2][4][128 * 64];   // 65536 B
    __shared__ __align__(16) char sB[2][4][64 * 64];    // 32768 B

    const int g = blockIdx.x;
    int bi = (int)((sqrtf(4.f * (float)g + 1.f) - 1.f) * 0.5f);
    while (bi > 0 && bi * (bi + 1) > g) --bi;
    while ((bi + 1) * (bi + 2) <= g) ++bi;
    const int bj = g - bi * (bi + 1);
    const int row0 = bi << 7, col0 = bj << 6;

    const int t = threadIdx.x;
    const int lane = t & 63, w = t >> 6;
    const int wr = w >> 1, wc = w & 1;          // 4x2 waves of 32x32

    const int ra = t >> 2;
    const int kca = (t & 3) ^ ((ra >> 1) & 3);
    const size_t aoff = (size_t)(row0 + ra) * 2048 + kca * 16;
    const int ldsAo = t * 16;
    const int tb = t & 255;
    const int rb = tb >> 2;
    const int kcb = (t & 3) ^ ((rb >> 1) & 3);
    const int hiw = (t >= 256) ? 1 : 0;
    const size_t boff = (size_t)(col0 + rb) * 2048 + kcb * 16 + hiw * 1024;
    const int ldsB0o = hiw * 8192 + tb * 16;
    const int ldsB1o = ldsB0o + 4096;

    const int m = lane & 15, gq = lane >> 4;
    const int fko = (gq ^ ((m >> 1) & 3)) * 16;

    i32x4 rehh[2][2], remx[2][2], iphh[2][2], ipmx[2][2], iqhh[2][2], iqmx[2][2];
    #pragma unroll
    for (int i = 0; i < 2; ++i)
        #pragma unroll
        for (int j = 0; j < 2; ++j) {
            rehh[i][j] = (i32x4){0, 0, 0, 0}; remx[i][j] = (i32x4){0, 0, 0, 0};
            iphh[i][j] = (i32x4){0, 0, 0, 0}; ipmx[i][j] = (i32x4){0, 0, 0, 0};
            iqhh[i][j] = (i32x4){0, 0, 0, 0}; iqmx[i][j] = (i32x4){0, 0, 0, 0};
        }

    char* const sA0 = &sA[0][0][0];
    char* const sB0 = &sB[0][0][0];

    // prologue: stage kt=0 into buffer 0
    load_lds16(Wh + aoff,        sA0 + ldsAo);
    load_lds16(Wl + aoff,        sA0 + 8192  + ldsAo);
    load_lds16(Wh + aoff + 1024, sA0 + 16384 + ldsAo);
    load_lds16(Wl + aoff + 1024, sA0 + 24576 + ldsAo);
    load_lds16(Wh + boff,        sB0 + ldsB0o);
    load_lds16(Wl + boff,        sB0 + ldsB1o);
    __syncthreads();

#define DO_MFMA_J(j)                                                          \
    _Pragma("unroll")                                                         \
    for (int i = 0; i < 2; ++i) {                                             \
        i32x4 r;                                                              \
        r = rehh[i][j];                                                       \
        r = MFMA_I8(fa1h[i], b1h[j], r, 0, 0, 0);                             \
        r = MFMA_I8(fa2h[i], b2h[j], r, 0, 0, 0);                             \
        rehh[i][j] = r;                                                       \
        r = remx[i][j];                                                       \
        r = MFMA_I8(fa1h[i], b1l[j], r, 0, 0, 0);                             \
        r = MFMA_I8(fa1l[i], b1h[j], r, 0, 0, 0);                             \
        r = MFMA_I8(fa2h[i], b2l[j], r, 0, 0, 0);                             \
        r = MFMA_I8(fa2l[i], b2h[j], r, 0, 0, 0);                             \
        remx[i][j] = r;                                                       \
        r = MFMA_I8(fa2h[i], b1h[j], iphh[i][j], 0, 0, 0); iphh[i][j] = r;    \
        r = ipmx[i][j];                                                       \
        r = MFMA_I8(fa2h[i], b1l[j], r, 0, 0, 0);                             \
        r = MFMA_I8(fa2l[i], b1h[j], r, 0, 0, 0);                             \
        ipmx[i][j] = r;                                                       \
        r = MFMA_I8(fa1h[i], b2h[j], iqhh[i][j], 0, 0, 0); iqhh[i][j] = r;    \
        r = iqmx[i][j];                                                       \
        r = MFMA_I8(fa1h[i], b2l[j], r, 0, 0, 0);                             \
        r = MFMA_I8(fa1l[i], b2h[j], r, 0, 0, 0);                             \
        iqmx[i][j] = r;                                                       \
    }

    #pragma unroll 2
    for (int kt = 0; kt < 16; ++kt) {
        const int cur = kt & 1;
        const char* sAc = sA0 + cur * 32768;
        const char* sBc = sB0 + cur * 16384;
        char* sAn = sA0 + (cur ^ 1) * 32768;
        char* sBn = sB0 + (cur ^ 1) * 16384;
        const size_t ko = (size_t)(kt + 1) * 64;

        // stage kt+1 first: readers of the target buffer finished at the
        // previous __syncthreads; drain at end of this kt is ~free.
        if (kt < 15) {
            load_lds16(Wh + aoff + ko,        sAn + ldsAo);
            load_lds16(Wl + aoff + ko,        sAn + 8192  + ldsAo);
            load_lds16(Wh + aoff + ko + 1024, sAn + 16384 + ldsAo);
            load_lds16(Wl + aoff + ko + 1024, sAn + 24576 + ldsAo);
            load_lds16(Wh + boff + ko, sBn + ldsB0o);
            load_lds16(Wl + boff + ko, sBn + ldsB1o);
        }

        i32x4 fa1h[2], fa1l[2], fa2h[2], fa2l[2];
        i32x4 b1h[2], b1l[2], b2h[2], b2l[2];
        #pragma unroll
        for (int i = 0; i < 2; ++i) {
            const int off = (wr * 32 + i * 16 + m) * 64 + fko;
            fa1h[i] = *(const i32x4*)(sAc + off);
            fa1l[i] = *(const i32x4*)(sAc + 8192  + off);
            fa2h[i] = *(const i32x4*)(sAc + 16384 + off);
            fa2l[i] = *(const i32x4*)(sAc + 24576 + off);
        }
        #pragma unroll
        for (int j = 0; j < 2; ++j) {
            const int off = (wc * 32 + j * 16 + m) * 64 + fko;
            b1h[j] = *(const i32x4*)(sBc + off);
            b1l[j] = *(const i32x4*)(sBc + 4096  + off);
            b2h[j] = *(const i32x4*)(sBc + 8192  + off);
            b2l[j] = *(const i32x4*)(sBc + 12288 + off);
        }

        __builtin_amdgcn_s_setprio(1);
        DO_MFMA_J(0)
        DO_MFMA_J(1)
        __builtin_amdgcn_s_setprio(0);

        // publishes kt+1 staging (vmcnt drain) + protects buffer swap
        __syncthreads();
    }
#undef DO_MFMA_J

    #pragma unroll
    for (int j = 0; j < 2; ++j) {
        const int col = col0 + wc * 32 + j * 16 + m;
        const float sc = g_scale[col];
        const int c64 = col >> 6;
        #pragma unroll
        for (int i = 0; i < 2; ++i) {
            #pragma unroll
            for (int r = 0; r < 4; ++r) {
                const int row = row0 + wr * 32 + i * 16 + gq * 4 + r;
                const float s2 = g_scale[row] * sc;
                const float re = s2 * (16384.f * (float)rehh[i][j][r] + 128.f * (float)remx[i][j][r]);
                const float im = s2 * (16384.f * (float)(iphh[i][j][r] - iqhh[i][j][r])
                                      + 128.f * (float)(ipmx[i][j][r] - iqmx[i][j][r]));
                const int r64 = row >> 6;
                if (r64 > c64 || row >= col) rho[(size_t)row * D + col] = make_float2(re, im);
                if (r64 == c64 && row > col) rho[(size_t)col * D + row] = make_float2(re, -im);
            }
        }
    }
}

// ---------------------------------------------------------------------------
__global__ void trace_inv(const float2* __restrict__ rho)
{
    __shared__ float red[256];
    float s = 0.f;
    for (int d = threadIdx.x; d < D; d += 256)
        s += rho[(size_t)d * (D + 1)].x;
    red[threadIdx.x] = s;
    __syncthreads();
    for (int off = 128; off > 0; off >>= 1) {
        if (threadIdx.x < off) red[threadIdx.x] += red[threadIdx.x + off];
        __syncthreads();
    }
    if (threadIdx.x == 0) g_inv_tr[0] = 1.0f / red[0];
}

// ---------------------------------------------------------------------------
// 2-qubit staged contraction on a 4x4 register tile (verified r9).
// ---------------------------------------------------------------------------
static __device__ __forceinline__ void qmt2(float2* x,
                                            const float* __restrict__ Mre,
                                            const float* __restrict__ Mim)
{
    float2 y[16];
    #pragma unroll
    for (int sb = 0; sb < 4; ++sb)
        #pragma unroll
        for (int ja = 0; ja < 2; ++ja)
            #pragma unroll
            for (int ia = 0; ia < 2; ++ia) {
                float2 acc = make_float2(0.f, 0.f);
                #pragma unroll
                for (int ib = 0; ib < 2; ++ib)
                    #pragma unroll
                    for (int jb = 0; jb < 2; ++jb) {
                        const float mr = Mre[sb * 4 + ib * 2 + jb];
                        const float mi = Mim[sb * 4 + ib * 2 + jb];
                        const float2 v = x[(ja * 2 + jb) * 4 + ia * 2 + ib];
                        acc.x += mr * v.x - mi * v.y;
                        acc.y += mr * v.y + mi * v.x;
                    }
                y[sb * 4 + ja * 2 + ia] = acc;
            }
    #pragma unroll
    for (int sa = 0; sa < 4; ++sa)
        #pragma unroll
        for (int sb = 0; sb < 4; ++sb) {
            float2 acc = make_float2(0.f, 0.f);
            #pragma unroll
            for (int ia = 0; ia < 2; ++ia)
                #pragma unroll
                for (int ja = 0; ja < 2; ++ja) {
                    const float mr = Mre[sa * 4 + ia * 2 + ja];
                    const float mi = Mim[sa * 4 + ia * 2 + ja];
                    const float2 v = y[sb * 4 + ja * 2 + ia];
                    acc.x += mr * v.x - mi * v.y;
                    acc.y += mr * v.y + mi * v.x;
                }
            x[sa * 4 + sb] = acc;
        }
}

// ---------------------------------------------------------------------------
static __device__ __forceinline__ void pA_pipeline(float2* x, float2* X, const int t,
                                                   const float* __restrict__ mre,
                                                   const float* __restrict__ mim)
{
    qmt2(x, mre, mim);
    #pragma unroll
    for (int d = 0; d < 16; ++d) X[t * 17 + d] = x[d];
    __syncthreads();
    const int a2 = t >> 6, t2 = (t >> 4) & 3, d1 = t & 15;
    #pragma unroll
    for (int j2 = 0; j2 < 4; ++j2)
        #pragma unroll
        for (int i2 = 0; i2 < 4; ++i2)
            x[j2 * 4 + i2] = X[((a2 * 4 + j2) * 16 + t2 * 4 + i2) * 17 + d1];
    __syncthreads();
    qmt2(x, mre, mim);
    #pragma unroll
    for (int d = 0; d < 16; ++d) X[(a2 * 4 + t2) * 257 + d * 16 + d1] = x[d];
    __syncthreads();
    const int e2 = t >> 4, e1 = t & 15;
    #pragma unroll
    for (int j2 = 0; j2 < 4; ++j2)
        #pragma unroll
        for (int i2 = 0; i2 < 4; ++i2)
            x[j2 * 4 + i2] = X[(j2 * 4 + i2) * 257 + e2 * 16 + e1];
    qmt2(x, mre, mim);
}

// ---------------------------------------------------------------------------
// Fused pass A, Hermitian (r10): lower-triangle tiles, 2080 groups.
// ---------------------------------------------------------------------------
__global__ __launch_bounds__(256) void qmt_pAh(const float2* __restrict__ in,
                                               float2* __restrict__ out,
                                               const float* __restrict__ Mre,
                                               const float* __restrict__ Mim)
{
    __shared__ __align__(16) float2 X[256 * 17];   // 34816 B
    const int t = threadIdx.x;
    const int g = blockIdx.x;
    int rr = (int)((sqrtf(8.f * (float)g + 1.f) - 1.f) * 0.5f);
    while (rr * (rr + 1) / 2 > g) --rr;
    while ((rr + 1) * (rr + 2) / 2 <= g) ++rr;
    const int cc = g - rr * (rr + 1) / 2;          // cc <= rr

    const int a4 = t >> 4, t4 = t & 15;
    float2 x0[16], x[16];
    #pragma unroll
    for (int j2 = 0; j2 < 4; ++j2) {
        const float2* p = in + ((size_t)(rr * 64 + a4 * 4 + j2)) * 4096 + cc * 64 + t4 * 4;
        const float4 v0 = ((const float4*)p)[0];
        const float4 v1 = ((const float4*)p)[1];
        x0[j2 * 4 + 0] = make_float2(v0.x, v0.y);
        x0[j2 * 4 + 1] = make_float2(v0.z, v0.w);
        x0[j2 * 4 + 2] = make_float2(v1.x, v1.y);
        x0[j2 * 4 + 3] = make_float2(v1.z, v1.w);
    }

    #pragma unroll
    for (int q = 0; q < 16; ++q) x[q] = x0[q];
    pA_pipeline(x, X, t, Mre, Mim);
    const int e2 = t >> 4, e1 = t & 15;
    const size_t ob0 = (size_t)(rr * 64 + cc) * 4096 + e2 * 16 + e1;
    #pragma unroll
    for (int d = 0; d < 16; ++d) out[ob0 + (size_t)d * 256] = x[d];

    if (rr != cc) {
        __syncthreads();
        #pragma unroll
        for (int q = 0; q < 16; ++q) x[q] = x0[q];
        pA_pipeline(x, X, t, g_mdre, g_mdim);
        const size_t ob1 = (size_t)(cc * 64 + rr) * 4096 + e2 * 16 + e1;
        #pragma unroll
        for (int d = 0; d < 16; ++d)
            out[ob1 + (size_t)d * 256] = make_float2(x[d].x, -x[d].y);
    }
}

// ---------------------------------------------------------------------------
// r13: half-tile 3-qubit contraction, float4-vectorized over 2 adjacent
// s-columns (col0 = .x/.y, col1 = .z/.w). Stages c,b local to ja-half;
// stage a combines halves via __shfl_xor(.,32).
// ---------------------------------------------------------------------------
static __device__ __forceinline__ void cmacc4(float4& a, const float mr, const float mi,
                                              const float4 v)
{
    a.x += mr * v.x - mi * v.y;
    a.y += mr * v.y + mi * v.x;
    a.z += mr * v.z - mi * v.w;
    a.w += mr * v.w + mi * v.z;
}

static __device__ __forceinline__ void qmt_stage_cb_half4(float4* x,
                                                          const float* __restrict__ Mre,
                                                          const float* __restrict__ Mim)
{
    // stage c — per jb block of 16
    #pragma unroll
    for (int jb = 0; jb < 2; ++jb) {
        float4 y[16];
        #pragma unroll
        for (int sc = 0; sc < 4; ++sc)
            #pragma unroll
            for (int ii = 0; ii < 4; ++ii) {
                float4 acc = make_float4(0.f, 0.f, 0.f, 0.f);
                #pragma unroll
                for (int ic = 0; ic < 2; ++ic)
                    #pragma unroll
                    for (int jc = 0; jc < 2; ++jc)
                        cmacc4(acc, Mre[sc * 4 + ic * 2 + jc], Mim[sc * 4 + ic * 2 + jc],
                               x[jb * 16 + jc * 8 + ii * 2 + ic]);
                y[sc * 4 + ii] = acc;
            }
        #pragma unroll
        for (int q = 0; q < 16; ++q) x[jb * 16 + q] = y[q];
    }
    // stage b — ja fixed to own half
    #pragma unroll
    for (int sc = 0; sc < 4; ++sc) {
        float4 z[8];
        #pragma unroll
        for (int sb = 0; sb < 4; ++sb)
            #pragma unroll
            for (int ia = 0; ia < 2; ++ia) {
                float4 acc = make_float4(0.f, 0.f, 0.f, 0.f);
                #pragma unroll
                for (int ib = 0; ib < 2; ++ib)
                    #pragma unroll
                    for (int jb = 0; jb < 2; ++jb)
                        cmacc4(acc, Mre[sb * 4 + ib * 2 + jb], Mim[sb * 4 + ib * 2 + jb],
                               x[jb * 16 + sc * 4 + ia * 2 + ib]);
                z[sb * 2 + ia] = acc;
            }
        #pragma unroll
        for (int sb = 0; sb < 4; ++sb)
            #pragma unroll
            for (int ia = 0; ia < 2; ++ia)
                x[(sb >> 1) * 16 + sc * 4 + ia * 2 + (sb & 1)] = z[sb * 2 + ia];
    }
}

// Stage-a coefficient rows for this thread's two sa values (sa = 2h + sal),
// own-half (A: ja = h) / partner-half (B: ja = 1-h) split baked in.
#define STAGE_A_COEFFS                                                        \
    float Are[2][2], Aim[2][2], Bre[2][2], Bim[2][2];                         \
    _Pragma("unroll")                                                         \
    for (int sal = 0; sal < 2; ++sal)                                         \
        _Pragma("unroll")                                                     \
        for (int ia = 0; ia < 2; ++ia) {                                      \
            const int sa = 2 * h + sal;                                       \
            Are[sal][ia] = Mre[sa * 4 + ia * 2 + h];                          \
            Aim[sal][ia] = Mim[sa * 4 + ia * 2 + h];                          \
            Bre[sal][ia] = Mre[sa * 4 + ia * 2 + (1 - h)];                    \
            Bim[sal][ia] = Mim[sa * 4 + ia * 2 + (1 - h)];                    \
        }

#define SHFL4(dst, src)                                                       \
    dst.x = __shfl_xor(src.x, 32); dst.y = __shfl_xor(src.y, 32);             \
    dst.z = __shfl_xor(src.z, 32); dst.w = __shfl_xor(src.w, 32);

// ---------------------------------------------------------------------------
// Pass B (= p3), r13: in [rr(64), cc(64), S(4096)]; out [r3,c3, s3(64), S].
// 1024 blocks x 256 threads; lane pair (l, l^32) shares one (r3,c3) tile and
// two adjacent s-columns; 32 float4 loads / 32 float4 stores per thread.
// ---------------------------------------------------------------------------
__global__ __launch_bounds__(256) void qmt_p3(const float2* __restrict__ in,
                                              float2* __restrict__ out,
                                              const float* __restrict__ Mre,
                                              const float* __restrict__ Mim)
{
    const int t = threadIdx.x;
    const int h = (t >> 5) & 1;
    const int idx = blockIdx.x * 4 + (t >> 6);     // [0, 4096)
    const int rc = idx >> 6;                       // [0, 64)
    const int r3 = rc >> 3, c3 = rc & 7;
    const int s = ((idx & 63) * 32 + (t & 31)) * 2;  // even, [0, 4096)

    float4 x[32];
    #pragma unroll
    for (int jb = 0; jb < 2; ++jb)
        #pragma unroll
        for (int jc = 0; jc < 2; ++jc) {
            const int j3 = 4 * h + 2 * jb + jc;
            #pragma unroll
            for (int i3 = 0; i3 < 8; ++i3)
                x[jb * 16 + jc * 8 + i3] = *(const float4*)
                    &in[(size_t)((r3 * 8 + j3) * 64 + c3 * 8 + i3) * 4096 + s];
        }

    qmt_stage_cb_half4(x, Mre, Mim);

    STAGE_A_COEFFS
    const size_t ob = ((size_t)(r3 * 8 + c3) * 64) * 4096 + s;
    #pragma unroll
    for (int sbH = 0; sbH < 2; ++sbH)
        #pragma unroll
        for (int sc = 0; sc < 4; ++sc)
            #pragma unroll
            for (int sbL = 0; sbL < 2; ++sbL) {
                const int q = sbH * 16 + sc * 4 + sbL;
                const float4 o0 = x[q], o1 = x[q + 2];
                float4 r0, r1;
                SHFL4(r0, o0)
                SHFL4(r1, o1)
                const int sb = sbH * 2 + sbL;
                #pragma unroll
                for (int sal = 0; sal < 2; ++sal) {
                    float4 res;
                    res.x = Are[sal][0] * o0.x - Aim[sal][0] * o0.y
                          + Are[sal][1] * o1.x - Aim[sal][1] * o1.y
                          + Bre[sal][0] * r0.x - Bim[sal][0] * r0.y
                          + Bre[sal][1] * r1.x - Bim[sal][1] * r1.y;
                    res.y = Are[sal][0] * o0.y + Aim[sal][0] * o0.x
                          + Are[sal][1] * o1.y + Aim[sal][1] * o1.x
                          + Bre[sal][0] * r0.y + Bim[sal][0] * r0.x
                          + Bre[sal][1] * r1.y + Bim[sal][1] * r1.x;
                    res.z = Are[sal][0] * o0.z - Aim[sal][0] * o0.w
                          + Are[sal][1] * o1.z - Aim[sal][1] * o1.w
                          + Bre[sal][0] * r0.z - Bim[sal][0] * r0.w
                          + Bre[sal][1] * r1.z - Bim[sal][1] * r1.w;
                    res.w = Are[sal][0] * o0.w + Aim[sal][0] * o0.z
                          + Are[sal][1] * o1.w + Aim[sal][1] * o1.z
                          + Bre[sal][0] * r0.w + Bim[sal][0] * r0.z
                          + Bre[sal][1] * r1.w + Bim[sal][1] * r1.z;
                    const int s3 = (2 * h + sal) * 16 + sb * 4 + sc;
                    *(float4*)&out[ob + (size_t)s3 * 4096] = res;
                }
            }
}

// ---------------------------------------------------------------------------
// Pass C (= p4, MSB triplet), r13: real-only out [s_hi, s3(64), s_lo(32)].
// 1024 blocks x 256 threads, 2 adjacent s per thread.
// ---------------------------------------------------------------------------
__global__ __launch_bounds__(256) void qmt_p4(const float2* __restrict__ in,
                                              float* __restrict__ out,
                                              const float* __restrict__ Mre,
                                              const float* __restrict__ Mim)
{
    const int t = threadIdx.x;
    const int h = (t >> 5) & 1;
    const int s = ((blockIdx.x * 4 + (t >> 6)) * 32 + (t & 31)) * 2;   // even, [0, 2^18)

    float4 x[32];
    #pragma unroll
    for (int jb = 0; jb < 2; ++jb)
        #pragma unroll
        for (int jc = 0; jc < 2; ++jc) {
            const int j3 = 4 * h + 2 * jb + jc;
            #pragma unroll
            for (int i3 = 0; i3 < 8; ++i3)
                x[jb * 16 + jc * 8 + i3] = *(const float4*)
                    &in[(size_t)(j3 * 8 + i3) * 262144 + s];
        }

    qmt_stage_cb_half4(x, Mre, Mim);

    STAGE_A_COEFFS
    const size_t ob = (size_t)(s >> 5) * 2048 + (s & 31);
    #pragma unroll
    for (int sbH = 0; sbH < 2; ++sbH)
        #pragma unroll
        for (int sc = 0; sc < 4; ++sc)
            #pragma unroll
            for (int sbL = 0; sbL < 2; ++sbL) {
                const int q = sbH * 16 + sc * 4 + sbL;
                const float4 o0 = x[q], o1 = x[q + 2];
                float4 r0, r1;
                SHFL4(r0, o0)
                SHFL4(r1, o1)
                const int sb = sbH * 2 + sbL;
                #pragma unroll
                for (int sal = 0; sal < 2; ++sal) {
                    float2 res;
                    res.x = Are[sal][0] * o0.x - Aim[sal][0] * o0.y
                          + Are[sal][1] * o1.x - Aim[sal][1] * o1.y
                          + Bre[sal][0] * r0.x - Bim[sal][0] * r0.y
                          + Bre[sal][1] * r1.x - Bim[sal][1] * r1.y;
                    res.y = Are[sal][0] * o0.z - Aim[sal][0] * o0.w
                          + Are[sal][1] * o1.z - Aim[sal][1] * o1.w
                          + Bre[sal][0] * r0.z - Bim[sal][0] * r0.w
                          + Bre[sal][1] * r1.z - Bim[sal][1] * r1.w;
                    const int s3 = (2 * h + sal) * 16 + sb * 4 + sc;
                    *(float2*)&out[ob + (size_t)s3 * 32] = res;
                }
            }
}

// ---------------------------------------------------------------------------
__global__ void gather_idx(const float* __restrict__ P, const int* __restrict__ idxs,
                           float* __restrict__ out, const int n)
{
    const int i = blockIdx.x * 256 + threadIdx.x;
    if (i < n) {
        const int idx = idxs[i];
        const int s = idx & 262143;
        const size_t pos = (size_t)(s >> 5) * 2048 + (size_t)(idx >> 18) * 32 + (s & 31);
        out[i] = P[pos] * g_inv_tr[0];
    }
}

// ---------------------------------------------------------------------------
extern "C" void kernel_launch(void* const* d_in, const int* in_sizes, int n_in,
                              void* d_out, int out_size, void* d_ws, size_t ws_size,
                              hipStream_t stream)
{
    const float* params = (const float*)d_in[0];  // (2, D, RANK) fp32
    const float* Mre    = (const float*)d_in[1];
    const float* Mim    = (const float*)d_in[2];
    const int*   idxs   = (const int*)d_in[3];
    float*       out    = (float*)d_out;

    float* ws = (float*)d_ws;
    float2* A  = (float2*)ws;                 // 134 MB plane
    float2* Bp = (float2*)(ws + 2 * NTOT);    // 134 MB plane
    char* Wh = (char*)Bp;
    char* Wl = Wh + (size_t)D * 2048;

    convert_w_i8<<<1024, 256, 0, stream>>>(params, Mre, Mim, Wh, Wl);
    gemm_rho_i8<<<1056, 512, 0, stream>>>(Wh, Wl, A);
    trace_inv<<<1, 256, 0, stream>>>(A);

    qmt_pAh<<<2080, 256, 0, stream>>>(A, Bp, Mre, Mim);  // 6 LSB qubits, triangle
    qmt_p3<<<1024, 256, 0, stream>>>(Bp, A, Mre, Mim);   // 3 qubits, float4 half-split
    qmt_p4<<<1024, 256, 0, stream>>>(A, (float*)Bp, Mre, Mim);  // 3 qubits, real out

    gather_idx<<<(out_size + 255) / 256, 256, 0, stream>>>((float*)Bp, idxs, out, out_size);
}

// Round 4
// 388.457 us; speedup vs baseline: 1.1215x; 1.1215x over previous
//
#include <hip/hip_runtime.h>

#define D 4096
#define RANK 1024
#define UELEMS 4194304ULL   // D*RANK
#define NTOT 16777216ULL    // 4^12 = D*D
#define QSCALE 16000.0f

typedef __attribute__((ext_vector_type(4))) int i32x4;

__device__ float g_inv_tr[1];
__device__ float g_scale[D];
__device__ float g_mdre[16];   // M-dagger tables: M†[s][i][j] = conj(M[s][j][i])
__device__ float g_mdim[16];

static __device__ __forceinline__ void load_lds16(const void* g, void* l) {
    __builtin_amdgcn_global_load_lds(
        (const __attribute__((address_space(1))) unsigned int*)g,
        (__attribute__((address_space(3))) unsigned int*)l, 16, 0, 0);
}

#define MFMA_I8 __builtin_amdgcn_mfma_i32_16x16x64_i8

// ---------------------------------------------------------------------------
// i8 split quantization of W = [Ur | Ui] with per-row scale (verified r6).
// ---------------------------------------------------------------------------
__global__ __launch_bounds__(256) void convert_w_i8(const float* __restrict__ P,
                                                    const float* __restrict__ Mre,
                                                    const float* __restrict__ Mim,
                                                    char* __restrict__ Wh,
                                                    char* __restrict__ Wl)
{
    if (blockIdx.x == 0 && threadIdx.x < 16) {
        const int s = threadIdx.x >> 2, i = (threadIdx.x >> 1) & 1, j = threadIdx.x & 1;
        g_mdre[threadIdx.x] =  Mre[s * 4 + j * 2 + i];
        g_mdim[threadIdx.x] = -Mim[s * 4 + j * 2 + i];
    }

    const int w = threadIdx.x >> 6, lane = threadIdx.x & 63;
    const int row = blockIdx.x * 4 + w;

    float ur[16], ui[16];
    const float* pr = P + (size_t)row * RANK + lane * 16;
    const float* pi = P + UELEMS + (size_t)row * RANK + lane * 16;
    #pragma unroll
    for (int q = 0; q < 4; ++q) {
        const float4 a = ((const float4*)pr)[q];
        const float4 b = ((const float4*)pi)[q];
        ur[q * 4 + 0] = a.x; ur[q * 4 + 1] = a.y; ur[q * 4 + 2] = a.z; ur[q * 4 + 3] = a.w;
        ui[q * 4 + 0] = b.x; ui[q * 4 + 1] = b.y; ui[q * 4 + 2] = b.z; ui[q * 4 + 3] = b.w;
    }
    float mx = 0.f;
    #pragma unroll
    for (int e = 0; e < 16; ++e)
        mx = fmaxf(mx, fmaxf(fabsf(ur[e]), fabsf(ui[e])));
    #pragma unroll
    for (int off = 1; off < 64; off <<= 1)
        mx = fmaxf(mx, __shfl_xor(mx, off));
    const float inv = mx > 0.f ? QSCALE / mx : 0.f;
    if (lane == 0) g_scale[row] = mx / QSCALE;

    int hr[16], lr[16], hi[16], li[16];
    #pragma unroll
    for (int e = 0; e < 16; ++e) {
        float q = ur[e] * inv;
        float hf = rintf(q * 0.0078125f);
        hr[e] = (int)hf; lr[e] = (int)rintf(q - 128.f * hf);
        q = ui[e] * inv;
        hf = rintf(q * 0.0078125f);
        hi[e] = (int)hf; li[e] = (int)rintf(q - 128.f * hf);
    }
    uint4 phr, plr, phi, pli;
    unsigned* dst[4] = {(unsigned*)&phr, (unsigned*)&plr, (unsigned*)&phi, (unsigned*)&pli};
    #pragma unroll
    for (int q = 0; q < 4; ++q) {
        unsigned a = 0, b = 0, c = 0, d = 0;
        #pragma unroll
        for (int k = 0; k < 4; ++k) {
            const int sh = k * 8;
            a |= (unsigned)(hr[q * 4 + k] & 255) << sh;
            b |= (unsigned)(lr[q * 4 + k] & 255) << sh;
            c |= (unsigned)(hi[q * 4 + k] & 255) << sh;
            d |= (unsigned)(li[q * 4 + k] & 255) << sh;
        }
        dst[0][q] = a; dst[1][q] = b; dst[2][q] = c; dst[3][q] = d;
    }
    const size_t b1 = (size_t)row * 2048 + lane * 16;
    *(uint4*)&Wh[b1] = phr;          *(uint4*)&Wl[b1] = plr;
    *(uint4*)&Wh[b1 + 1024] = phi;   *(uint4*)&Wl[b1 + 1024] = pli;
}

// ---------------------------------------------------------------------------
// Fused Hermitian GEMM in i8. r14: 64x64 tile, 256 threads (2x2 waves of
// 32x32), double-buffered LDS = 64 KB -> TWO independent blocks per CU.
// r11/r13 post-mortem: at 1 block/CU every schedule (barriered or not) left
// MfmaUtil at ~35% because all resident waves enter the ds_read burst and the
// MFMA burst together; co-residency of 2 unsynchronized blocks lets one
// block's MFMA hide the other's staging/LDS phase (m114 mechanism).
// 2080 lower-triangle 64-tiles; im = P - Q (exact int) in epilogue.
// ---------------------------------------------------------------------------
__global__ __launch_bounds__(256, 2) void gemm_rho_i8(const char* __restrict__ Wh,
                                                      const char* __restrict__ Wl,
                                                      float2* __restrict__ rho)
{
    __shared__ __align__(16) char sA[2][4][64 * 64];   // 32768 B
    __shared__ __align__(16) char sB[2][4][64 * 64];   // 32768 B

    const int g = blockIdx.x;                  // 2080 triangle tiles, bi >= bj
    int bi = (int)((sqrtf(8.f * (float)g + 1.f) - 1.f) * 0.5f);
    while (bi * (bi + 1) / 2 > g) --bi;
    while ((bi + 1) * (bi + 2) / 2 <= g) ++bi;
    const int bj = g - bi * (bi + 1) / 2;
    const int row0 = bi << 6, col0 = bj << 6;

    const int t = threadIdx.x;
    const int lane = t & 63, w = t >> 6;
    const int wr = w >> 1, wc = w & 1;          // 2x2 waves of 32x32

    // staging: 64 rows x 64 B per plane; thread t covers row t>>2, slot t&3
    const int ra = t >> 2;
    const int kca = (t & 3) ^ ((ra >> 1) & 3);  // xor-swizzled k-slot
    const size_t aoff = (size_t)(row0 + ra) * 2048 + kca * 16;
    const size_t boff = (size_t)(col0 + ra) * 2048 + kca * 16;
    const int ldso = t * 16;                    // linear LDS dest within plane

    const int m = lane & 15, gq = lane >> 4;
    const int fko = (gq ^ ((m >> 1) & 3)) * 16;

    i32x4 rehh[2][2], remx[2][2], iphh[2][2], ipmx[2][2], iqhh[2][2], iqmx[2][2];
    #pragma unroll
    for (int i = 0; i < 2; ++i)
        #pragma unroll
        for (int j = 0; j < 2; ++j) {
            rehh[i][j] = (i32x4){0, 0, 0, 0}; remx[i][j] = (i32x4){0, 0, 0, 0};
            iphh[i][j] = (i32x4){0, 0, 0, 0}; ipmx[i][j] = (i32x4){0, 0, 0, 0};
            iqhh[i][j] = (i32x4){0, 0, 0, 0}; iqmx[i][j] = (i32x4){0, 0, 0, 0};
        }

    char* const sA0 = &sA[0][0][0];
    char* const sB0 = &sB[0][0][0];

    // prologue: stage kt=0 into buffer 0
    load_lds16(Wh + aoff,        sA0 + ldso);
    load_lds16(Wl + aoff,        sA0 + 4096  + ldso);
    load_lds16(Wh + aoff + 1024, sA0 + 8192  + ldso);
    load_lds16(Wl + aoff + 1024, sA0 + 12288 + ldso);
    load_lds16(Wh + boff,        sB0 + ldso);
    load_lds16(Wl + boff,        sB0 + 4096  + ldso);
    load_lds16(Wh + boff + 1024, sB0 + 8192  + ldso);
    load_lds16(Wl + boff + 1024, sB0 + 12288 + ldso);
    __syncthreads();

#define DO_MFMA_J(j)                                                          \
    _Pragma("unroll")                                                         \
    for (int i = 0; i < 2; ++i) {                                             \
        i32x4 r;                                                              \
        r = rehh[i][j];                                                       \
        r = MFMA_I8(fa1h[i], b1h[j], r, 0, 0, 0);                             \
        r = MFMA_I8(fa2h[i], b2h[j], r, 0, 0, 0);                             \
        rehh[i][j] = r;                                                       \
        r = remx[i][j];                                                       \
        r = MFMA_I8(fa1h[i], b1l[j], r, 0, 0, 0);                             \
        r = MFMA_I8(fa1l[i], b1h[j], r, 0, 0, 0);                             \
        r = MFMA_I8(fa2h[i], b2l[j], r, 0, 0, 0);                             \
        r = MFMA_I8(fa2l[i], b2h[j], r, 0, 0, 0);                             \
        remx[i][j] = r;                                                       \
        r = MFMA_I8(fa2h[i], b1h[j], iphh[i][j], 0, 0, 0); iphh[i][j] = r;    \
        r = ipmx[i][j];                                                       \
        r = MFMA_I8(fa2h[i], b1l[j], r, 0, 0, 0);                             \
        r = MFMA_I8(fa2l[i], b1h[j], r, 0, 0, 0);                             \
        ipmx[i][j] = r;                                                       \
        r = MFMA_I8(fa1h[i], b2h[j], iqhh[i][j], 0, 0, 0); iqhh[i][j] = r;    \
        r = iqmx[i][j];                                                       \
        r = MFMA_I8(fa1h[i], b2l[j], r, 0, 0, 0);                             \
        r = MFMA_I8(fa1l[i], b2h[j], r, 0, 0, 0);                             \
        iqmx[i][j] = r;                                                       \
    }

    #pragma unroll 2
    for (int kt = 0; kt < 16; ++kt) {
        const int cur = kt & 1;
        const char* sAc = sA0 + cur * 16384;
        const char* sBc = sB0 + cur * 16384;
        char* sAn = sA0 + (cur ^ 1) * 16384;
        char* sBn = sB0 + (cur ^ 1) * 16384;
        const size_t ko = (size_t)(kt + 1) * 64;

        // stage kt+1 first: readers of the target buffer finished at the
        // previous __syncthreads; the end-of-kt drain sits behind compute.
        if (kt < 15) {
            load_lds16(Wh + aoff + ko,        sAn + ldso);
            load_lds16(Wl + aoff + ko,        sAn + 4096  + ldso);
            load_lds16(Wh + aoff + ko + 1024, sAn + 8192  + ldso);
            load_lds16(Wl + aoff + ko + 1024, sAn + 12288 + ldso);
            load_lds16(Wh + boff + ko,        sBn + ldso);
            load_lds16(Wl + boff + ko,        sBn + 4096  + ldso);
            load_lds16(Wh + boff + ko + 1024, sBn + 8192  + ldso);
            load_lds16(Wl + boff + ko + 1024, sBn + 12288 + ldso);
        }

        i32x4 fa1h[2], fa1l[2], fa2h[2], fa2l[2];
        i32x4 b1h[2], b1l[2], b2h[2], b2l[2];
        #pragma unroll
        for (int i = 0; i < 2; ++i) {
            const int off = (wr * 32 + i * 16 + m) * 64 + fko;
            fa1h[i] = *(const i32x4*)(sAc + off);
            fa1l[i] = *(const i32x4*)(sAc + 4096  + off);
            fa2h[i] = *(const i32x4*)(sAc + 8192  + off);
            fa2l[i] = *(const i32x4*)(sAc + 12288 + off);
        }
        #pragma unroll
        for (int j = 0; j < 2; ++j) {
            const int off = (wc * 32 + j * 16 + m) * 64 + fko;
            b1h[j] = *(const i32x4*)(sBc + off);
            b1l[j] = *(const i32x4*)(sBc + 4096  + off);
            b2h[j] = *(const i32x4*)(sBc + 8192  + off);
            b2l[j] = *(const i32x4*)(sBc + 12288 + off);
        }

        __builtin_amdgcn_s_setprio(1);
        DO_MFMA_J(0)
        DO_MFMA_J(1)
        __builtin_amdgcn_s_setprio(0);

        // publishes kt+1 staging (vmcnt drain) + protects buffer swap
        __syncthreads();
    }
#undef DO_MFMA_J

    #pragma unroll
    for (int j = 0; j < 2; ++j) {
        const int col = col0 + wc * 32 + j * 16 + m;
        const float sc = g_scale[col];
        const int c64 = col >> 6;
        #pragma unroll
        for (int i = 0; i < 2; ++i) {
            #pragma unroll
            for (int r = 0; r < 4; ++r) {
                const int row = row0 + wr * 32 + i * 16 + gq * 4 + r;
                const float s2 = g_scale[row] * sc;
                const float re = s2 * (16384.f * (float)rehh[i][j][r] + 128.f * (float)remx[i][j][r]);
                const float im = s2 * (16384.f * (float)(iphh[i][j][r] - iqhh[i][j][r])
                                      + 128.f * (float)(ipmx[i][j][r] - iqmx[i][j][r]));
                const int r64 = row >> 6;
                if (r64 > c64 || row >= col) rho[(size_t)row * D + col] = make_float2(re, im);
                if (r64 == c64 && row > col) rho[(size_t)col * D + row] = make_float2(re, -im);
            }
        }
    }
}

// ---------------------------------------------------------------------------
__global__ void trace_inv(const float2* __restrict__ rho)
{
    __shared__ float red[256];
    float s = 0.f;
    for (int d = threadIdx.x; d < D; d += 256)
        s += rho[(size_t)d * (D + 1)].x;
    red[threadIdx.x] = s;
    __syncthreads();
    for (int off = 128; off > 0; off >>= 1) {
        if (threadIdx.x < off) red[threadIdx.x] += red[threadIdx.x + off];
        __syncthreads();
    }
    if (threadIdx.x == 0) g_inv_tr[0] = 1.0f / red[0];
}

// ---------------------------------------------------------------------------
// 2-qubit staged contraction on a 4x4 register tile (verified r9).
// ---------------------------------------------------------------------------
static __device__ __forceinline__ void qmt2(float2* x,
                                            const float* __restrict__ Mre,
                                            const float* __restrict__ Mim)
{
    float2 y[16];
    #pragma unroll
    for (int sb = 0; sb < 4; ++sb)
        #pragma unroll
        for (int ja = 0; ja < 2; ++ja)
            #pragma unroll
            for (int ia = 0; ia < 2; ++ia) {
                float2 acc = make_float2(0.f, 0.f);
                #pragma unroll
                for (int ib = 0; ib < 2; ++ib)
                    #pragma unroll
                    for (int jb = 0; jb < 2; ++jb) {
                        const float mr = Mre[sb * 4 + ib * 2 + jb];
                        const float mi = Mim[sb * 4 + ib * 2 + jb];
                        const float2 v = x[(ja * 2 + jb) * 4 + ia * 2 + ib];
                        acc.x += mr * v.x - mi * v.y;
                        acc.y += mr * v.y + mi * v.x;
                    }
                y[sb * 4 + ja * 2 + ia] = acc;
            }
    #pragma unroll
    for (int sa = 0; sa < 4; ++sa)
        #pragma unroll
        for (int sb = 0; sb < 4; ++sb) {
            float2 acc = make_float2(0.f, 0.f);
            #pragma unroll
            for (int ia = 0; ia < 2; ++ia)
                #pragma unroll
                for (int ja = 0; ja < 2; ++ja) {
                    const float mr = Mre[sa * 4 + ia * 2 + ja];
                    const float mi = Mim[sa * 4 + ia * 2 + ja];
                    const float2 v = y[sb * 4 + ja * 2 + ia];
                    acc.x += mr * v.x - mi * v.y;
                    acc.y += mr * v.y + mi * v.x;
                }
            x[sa * 4 + sb] = acc;
        }
}

// ---------------------------------------------------------------------------
static __device__ __forceinline__ void pA_pipeline(float2* x, float2* X, const int t,
                                                   const float* __restrict__ mre,
                                                   const float* __restrict__ mim)
{
    qmt2(x, mre, mim);
    #pragma unroll
    for (int d = 0; d < 16; ++d) X[t * 17 + d] = x[d];
    __syncthreads();
    const int a2 = t >> 6, t2 = (t >> 4) & 3, d1 = t & 15;
    #pragma unroll
    for (int j2 = 0; j2 < 4; ++j2)
        #pragma unroll
        for (int i2 = 0; i2 < 4; ++i2)
            x[j2 * 4 + i2] = X[((a2 * 4 + j2) * 16 + t2 * 4 + i2) * 17 + d1];
    __syncthreads();
    qmt2(x, mre, mim);
    #pragma unroll
    for (int d = 0; d < 16; ++d) X[(a2 * 4 + t2) * 257 + d * 16 + d1] = x[d];
    __syncthreads();
    const int e2 = t >> 4, e1 = t & 15;
    #pragma unroll
    for (int j2 = 0; j2 < 4; ++j2)
        #pragma unroll
        for (int i2 = 0; i2 < 4; ++i2)
            x[j2 * 4 + i2] = X[(j2 * 4 + i2) * 257 + e2 * 16 + e1];
    qmt2(x, mre, mim);
}

// ---------------------------------------------------------------------------
// Fused pass A, Hermitian (r10): lower-triangle tiles, 2080 groups.
// ---------------------------------------------------------------------------
__global__ __launch_bounds__(256) void qmt_pAh(const float2* __restrict__ in,
                                               float2* __restrict__ out,
                                               const float* __restrict__ Mre,
                                               const float* __restrict__ Mim)
{
    __shared__ __align__(16) float2 X[256 * 17];   // 34816 B
    const int t = threadIdx.x;
    const int g = blockIdx.x;
    int rr = (int)((sqrtf(8.f * (float)g + 1.f) - 1.f) * 0.5f);
    while (rr * (rr + 1) / 2 > g) --rr;
    while ((rr + 1) * (rr + 2) / 2 <= g) ++rr;
    const int cc = g - rr * (rr + 1) / 2;          // cc <= rr

    const int a4 = t >> 4, t4 = t & 15;
    float2 x0[16], x[16];
    #pragma unroll
    for (int j2 = 0; j2 < 4; ++j2) {
        const float2* p = in + ((size_t)(rr * 64 + a4 * 4 + j2)) * 4096 + cc * 64 + t4 * 4;
        const float4 v0 = ((const float4*)p)[0];
        const float4 v1 = ((const float4*)p)[1];
        x0[j2 * 4 + 0] = make_float2(v0.x, v0.y);
        x0[j2 * 4 + 1] = make_float2(v0.z, v0.w);
        x0[j2 * 4 + 2] = make_float2(v1.x, v1.y);
        x0[j2 * 4 + 3] = make_float2(v1.z, v1.w);
    }

    #pragma unroll
    for (int q = 0; q < 16; ++q) x[q] = x0[q];
    pA_pipeline(x, X, t, Mre, Mim);
    const int e2 = t >> 4, e1 = t & 15;
    const size_t ob0 = (size_t)(rr * 64 + cc) * 4096 + e2 * 16 + e1;
    #pragma unroll
    for (int d = 0; d < 16; ++d) out[ob0 + (size_t)d * 256] = x[d];

    if (rr != cc) {
        __syncthreads();
        #pragma unroll
        for (int q = 0; q < 16; ++q) x[q] = x0[q];
        pA_pipeline(x, X, t, g_mdre, g_mdim);
        const size_t ob1 = (size_t)(cc * 64 + rr) * 4096 + e2 * 16 + e1;
        #pragma unroll
        for (int d = 0; d < 16; ++d)
            out[ob1 + (size_t)d * 256] = make_float2(x[d].x, -x[d].y);
    }
}

// ---------------------------------------------------------------------------
// r12 half-tile 3-qubit contraction (verified round-2 WIN; r13 float4
// widening reverted — VGPR cliff). Each thread owns the ja = h half (32 of
// 64 tile elements); stages c,b local; stage a combines via __shfl_xor(.,32).
// ---------------------------------------------------------------------------
static __device__ __forceinline__ void qmt_stage_cb_half(float2* x,
                                                         const float* __restrict__ Mre,
                                                         const float* __restrict__ Mim)
{
    #pragma unroll
    for (int jb = 0; jb < 2; ++jb) {
        float2 y[16];
        #pragma unroll
        for (int sc = 0; sc < 4; ++sc)
            #pragma unroll
            for (int ii = 0; ii < 4; ++ii) {
                float2 acc = make_float2(0.f, 0.f);
                #pragma unroll
                for (int ic = 0; ic < 2; ++ic)
                    #pragma unroll
                    for (int jc = 0; jc < 2; ++jc) {
                        const float mr = Mre[sc * 4 + ic * 2 + jc];
                        const float mi = Mim[sc * 4 + ic * 2 + jc];
                        const float2 v = x[jb * 16 + jc * 8 + ii * 2 + ic];
                        acc.x += mr * v.x - mi * v.y;
                        acc.y += mr * v.y + mi * v.x;
                    }
                y[sc * 4 + ii] = acc;
            }
        #pragma unroll
        for (int q = 0; q < 16; ++q) x[jb * 16 + q] = y[q];
    }
    #pragma unroll
    for (int sc = 0; sc < 4; ++sc) {
        float2 z[8];
        #pragma unroll
        for (int sb = 0; sb < 4; ++sb)
            #pragma unroll
            for (int ia = 0; ia < 2; ++ia) {
                float2 acc = make_float2(0.f, 0.f);
                #pragma unroll
                for (int ib = 0; ib < 2; ++ib)
                    #pragma unroll
                    for (int jb = 0; jb < 2; ++jb) {
                        const float mr = Mre[sb * 4 + ib * 2 + jb];
                        const float mi = Mim[sb * 4 + ib * 2 + jb];
                        const float2 v = x[jb * 16 + sc * 4 + ia * 2 + ib];
                        acc.x += mr * v.x - mi * v.y;
                        acc.y += mr * v.y + mi * v.x;
                    }
                z[sb * 2 + ia] = acc;
            }
        #pragma unroll
        for (int sb = 0; sb < 4; ++sb)
            #pragma unroll
            for (int ia = 0; ia < 2; ++ia)
                x[(sb >> 1) * 16 + sc * 4 + ia * 2 + (sb & 1)] = z[sb * 2 + ia];
    }
}

#define STAGE_A_COEFFS                                                        \
    float Are[2][2], Aim[2][2], Bre[2][2], Bim[2][2];                         \
    _Pragma("unroll")                                                         \
    for (int sal = 0; sal < 2; ++sal)                                         \
        _Pragma("unroll")                                                     \
        for (int ia = 0; ia < 2; ++ia) {                                      \
            const int sa = 2 * h + sal;                                       \
            Are[sal][ia] = Mre[sa * 4 + ia * 2 + h];                          \
            Aim[sal][ia] = Mim[sa * 4 + ia * 2 + h];                          \
            Bre[sal][ia] = Mre[sa * 4 + ia * 2 + (1 - h)];                    \
            Bim[sal][ia] = Mim[sa * 4 + ia * 2 + (1 - h)];                    \
        }

// ---------------------------------------------------------------------------
// Pass B (= p3), r12: in [rr(64), cc(64), S(4096)]; out [r3,c3, s3(64), S].
// 2048 blocks x 256 threads; lane pair (l, l^32) shares one (r3,c3,s) tile.
// ---------------------------------------------------------------------------
__global__ __launch_bounds__(256) void qmt_p3(const float2* __restrict__ in,
                                              float2* __restrict__ out,
                                              const float* __restrict__ Mre,
                                              const float* __restrict__ Mim)
{
    const int t = threadIdx.x;
    const int h = (t >> 5) & 1;
    const int idx = blockIdx.x * 4 + (t >> 6);     // [0, 8192)
    const int rc = idx >> 7;                       // [0, 64)
    const int r3 = rc >> 3, c3 = rc & 7;
    const int s = (idx & 127) * 32 + (t & 31);     // [0, 4096)

    float2 x[32];
    #pragma unroll
    for (int jb = 0; jb < 2; ++jb)
        #pragma unroll
        for (int jc = 0; jc < 2; ++jc) {
            const int j3 = 4 * h + 2 * jb + jc;
            #pragma unroll
            for (int i3 = 0; i3 < 8; ++i3)
                x[jb * 16 + jc * 8 + i3] =
                    in[(size_t)((r3 * 8 + j3) * 64 + c3 * 8 + i3) * 4096 + s];
        }

    qmt_stage_cb_half(x, Mre, Mim);

    STAGE_A_COEFFS
    const size_t ob = ((size_t)(r3 * 8 + c3) * 64) * 4096 + s;
    #pragma unroll
    for (int sbH = 0; sbH < 2; ++sbH)
        #pragma unroll
        for (int sc = 0; sc < 4; ++sc)
            #pragma unroll
            for (int sbL = 0; sbL < 2; ++sbL) {
                const int q = sbH * 16 + sc * 4 + sbL;
                const float2 o0 = x[q], o1 = x[q + 2];
                float2 r0, r1;
                r0.x = __shfl_xor(o0.x, 32); r0.y = __shfl_xor(o0.y, 32);
                r1.x = __shfl_xor(o1.x, 32); r1.y = __shfl_xor(o1.y, 32);
                const int sb = sbH * 2 + sbL;
                #pragma unroll
                for (int sal = 0; sal < 2; ++sal) {
                    const float re = Are[sal][0] * o0.x - Aim[sal][0] * o0.y
                                   + Are[sal][1] * o1.x - Aim[sal][1] * o1.y
                                   + Bre[sal][0] * r0.x - Bim[sal][0] * r0.y
                                   + Bre[sal][1] * r1.x - Bim[sal][1] * r1.y;
                    const float im = Are[sal][0] * o0.y + Aim[sal][0] * o0.x
                                   + Are[sal][1] * o1.y + Aim[sal][1] * o1.x
                                   + Bre[sal][0] * r0.y + Bim[sal][0] * r0.x
                                   + Bre[sal][1] * r1.y + Bim[sal][1] * r1.x;
                    const int s3 = (2 * h + sal) * 16 + sb * 4 + sc;
                    out[ob + (size_t)s3 * 4096] = make_float2(re, im);
                }
            }
}

// ---------------------------------------------------------------------------
// Pass C (= p4, MSB triplet), r12: real-only out [s_hi, s3(64), s_lo(32)].
// 2048 blocks x 256 threads.
// ---------------------------------------------------------------------------
__global__ __launch_bounds__(256) void qmt_p4(const float2* __restrict__ in,
                                              float* __restrict__ out,
                                              const float* __restrict__ Mre,
                                              const float* __restrict__ Mim)
{
    const int t = threadIdx.x;
    const int h = (t >> 5) & 1;
    const int s = (blockIdx.x * 4 + (t >> 6)) * 32 + (t & 31);   // [0, 2^18)

    float2 x[32];
    #pragma unroll
    for (int jb = 0; jb < 2; ++jb)
        #pragma unroll
        for (int jc = 0; jc < 2; ++jc) {
            const int j3 = 4 * h + 2 * jb + jc;
            #pragma unroll
            for (int i3 = 0; i3 < 8; ++i3)
                x[jb * 16 + jc * 8 + i3] = in[(size_t)(j3 * 8 + i3) * 262144 + s];
        }

    qmt_stage_cb_half(x, Mre, Mim);

    STAGE_A_COEFFS
    const size_t ob = (size_t)(s >> 5) * 2048 + (s & 31);
    #pragma unroll
    for (int sbH = 0; sbH < 2; ++sbH)
        #pragma unroll
        for (int sc = 0; sc < 4; ++sc)
            #pragma unroll
            for (int sbL = 0; sbL < 2; ++sbL) {
                const int q = sbH * 16 + sc * 4 + sbL;
                const float2 o0 = x[q], o1 = x[q + 2];
                float2 r0, r1;
                r0.x = __shfl_xor(o0.x, 32); r0.y = __shfl_xor(o0.y, 32);
                r1.x = __shfl_xor(o1.x, 32); r1.y = __shfl_xor(o1.y, 32);
                const int sb = sbH * 2 + sbL;
                #pragma unroll
                for (int sal = 0; sal < 2; ++sal) {
                    const float re = Are[sal][0] * o0.x - Aim[sal][0] * o0.y
                                   + Are[sal][1] * o1.x - Aim[sal][1] * o1.y
                                   + Bre[sal][0] * r0.x - Bim[sal][0] * r0.y
                                   + Bre[sal][1] * r1.x - Bim[sal][1] * r1.y;
                    const int s3 = (2 * h + sal) * 16 + sb * 4 + sc;
                    out[ob + (size_t)s3 * 32] = re;
                }
            }
}

// ---------------------------------------------------------------------------
__global__ void gather_idx(const float* __restrict__ P, const int* __restrict__ idxs,
                           float* __restrict__ out, const int n)
{
    const int i = blockIdx.x * 256 + threadIdx.x;
    if (i < n) {
        const int idx = idxs[i];
        const int s = idx & 262143;
        const size_t pos = (size_t)(s >> 5) * 2048 + (size_t)(idx >> 18) * 32 + (s & 31);
        out[i] = P[pos] * g_inv_tr[0];
    }
}

// ---------------------------------------------------------------------------
extern "C" void kernel_launch(void* const* d_in, const int* in_sizes, int n_in,
                              void* d_out, int out_size, void* d_ws, size_t ws_size,
                              hipStream_t stream)
{
    const float* params = (const float*)d_in[0];  // (2, D, RANK) fp32
    const float* Mre    = (const float*)d_in[1];
    const float* Mim    = (const float*)d_in[2];
    const int*   idxs   = (const int*)d_in[3];
    float*       out    = (float*)d_out;

    float* ws = (float*)d_ws;
    float2* A  = (float2*)ws;                 // 134 MB plane
    float2* Bp = (float2*)(ws + 2 * NTOT);    // 134 MB plane
    char* Wh = (char*)Bp;
    char* Wl = Wh + (size_t)D * 2048;

    convert_w_i8<<<1024, 256, 0, stream>>>(params, Mre, Mim, Wh, Wl);
    gemm_rho_i8<<<2080, 256, 0, stream>>>(Wh, Wl, A);
    trace_inv<<<1, 256, 0, stream>>>(A);

    qmt_pAh<<<2080, 256, 0, stream>>>(A, Bp, Mre, Mim);  // 6 LSB qubits, triangle
    qmt_p3<<<2048, 256, 0, stream>>>(Bp, A, Mre, Mim);   // 3 qubits, half-split
    qmt_p4<<<2048, 256, 0, stream>>>(A, (float*)Bp, Mre, Mim);  // 3 qubits, real out

    gather_idx<<<(out_size + 255) / 256, 256, 0, stream>>>((float*)Bp, idxs, out, out_size);
}